// Round 12
// baseline (2460.483 us; speedup 1.0000x reference)
//
#include <hip/hip_runtime.h>
#include <hip/hip_bf16.h>

#define T2 2048
#define H2 256
#define BT2 131072          // B*T = 64*2048
#define MAXP 4

typedef __attribute__((ext_vector_type(8))) short bf16x8;
typedef __attribute__((ext_vector_type(4))) float f32x4;
typedef unsigned short u16;

__device__ __forceinline__ u16 f2bf(float f) {
    union { float f; unsigned u; } v; v.f = f;
    unsigned r = (v.u + 0x7FFFu + ((v.u >> 16) & 1u)) >> 16;
    return (u16)r;
}
__device__ __forceinline__ void async16(const void* g, void* l) {
    __builtin_amdgcn_global_load_lds((const __attribute__((address_space(1))) void*)g,
                                     (__attribute__((address_space(3))) void*)l, 16, 0, 0);
}
__device__ __forceinline__ float frcp(float x) { return __builtin_amdgcn_rcpf(x); }
__device__ __forceinline__ float sig_f(float x) { return frcp(1.f + __expf(-x)); }
__device__ __forceinline__ float tanh_f(float x) {
    return 1.f - 2.f * frcp(__expf(2.f * x) + 1.f);
}

// f32 -> bf16 cast, 4 elems/thread (adjacency only)
__global__ __launch_bounds__(256) void cast_bf16_k(
    const float* __restrict__ in, u16* __restrict__ out, int n4)
{
    const int i = blockIdx.x * 256 + threadIdx.x;
    if (i >= n4) return;
    const float4 v = ((const float4*)in)[i];
    ushort4 h;
    h.x = f2bf(v.x); h.y = f2bf(v.y); h.z = f2bf(v.z); h.w = f2bf(v.w);
    ((ushort4*)out)[i] = h;
}

// ---------------------------------------------------------------------------
// Support GEMM 1, fused f32-A (unchanged from R10).
// ---------------------------------------------------------------------------
__global__ __launch_bounds__(256) void bgemm_sup_f32a_k(
    const float* __restrict__ A, const u16* __restrict__ Bt,
    const float* __restrict__ bias, u16* __restrict__ Ct)
{
    __shared__ __align__(16) u16 As[2][128][64];
    __shared__ __align__(16) u16 Bs[2][128][64];
    const int K = 256;

    const int tid = threadIdx.x;
    const int wid = tid >> 6, lane = tid & 63;
    const int wr = wid >> 1, wc = wid & 1;
    const int bx = blockIdx.x >> 1, by = blockIdx.x & 1;
    const int row0 = bx * 128, col0 = by * 128;

    const int srow = tid >> 3;
    const int skA = ((tid ^ srow) & 7) << 3;
    const float* Agf = A + (size_t)(row0 + srow) * K + skA;
    const u16* Bg = Bt + (size_t)(col0 + srow) * K + skA;
    char* ldsA = (char*)&As[0][0][0];
    char* ldsB = (char*)&Bs[0][0][0];
    const int wb = wid << 10;
    const int awr = srow * 128 + (tid & 7) * 16;

    f32x4 acc[4][4];
    #pragma unroll
    for (int i = 0; i < 4; ++i)
        #pragma unroll
        for (int q = 0; q < 4; ++q) acc[i][q] = (f32x4){0.f, 0.f, 0.f, 0.f};

    #pragma unroll
    for (int s = 0; s < 4; ++s) {
        const float4 u0 = *(const float4*)(Agf + (size_t)(s * 32) * K);
        const float4 u1 = *(const float4*)(Agf + (size_t)(s * 32) * K + 4);
        ushort4 h0, h1;
        h0.x = f2bf(u0.x); h0.y = f2bf(u0.y); h0.z = f2bf(u0.z); h0.w = f2bf(u0.w);
        h1.x = f2bf(u1.x); h1.y = f2bf(u1.y); h1.z = f2bf(u1.z); h1.w = f2bf(u1.w);
        *(ushort4*)(ldsA + s * 4096 + awr) = h0;
        *(ushort4*)(ldsA + s * 4096 + awr + 8) = h1;
        async16(Bg + (size_t)(s * 32) * K, ldsB + s * 4096 + wb);
    }
    __syncthreads();

    int cur = 0;
    for (int k0 = 0; k0 < K; k0 += 64) {
        if (k0 + 64 < K) {
            char* dA = ldsA + ((cur ^ 1) << 14);
            char* dB = ldsB + ((cur ^ 1) << 14);
            #pragma unroll
            for (int s = 0; s < 4; ++s) {
                const float4 u0 = *(const float4*)(Agf + (size_t)(s * 32) * K + k0 + 64);
                const float4 u1 = *(const float4*)(Agf + (size_t)(s * 32) * K + k0 + 68);
                ushort4 h0, h1;
                h0.x = f2bf(u0.x); h0.y = f2bf(u0.y); h0.z = f2bf(u0.z); h0.w = f2bf(u0.w);
                h1.x = f2bf(u1.x); h1.y = f2bf(u1.y); h1.z = f2bf(u1.z); h1.w = f2bf(u1.w);
                *(ushort4*)(dA + s * 4096 + awr) = h0;
                *(ushort4*)(dA + s * 4096 + awr + 8) = h1;
                async16(Bg + (size_t)(s * 32) * K + k0 + 64, dB + s * 4096 + wb);
            }
        }
        char* rA = ldsA + (cur << 14);
        char* rB = ldsB + (cur << 14);
        const int mb = lane & 15, g = lane >> 4;
        #pragma unroll
        for (int kk = 0; kk < 2; ++kk) {
            bf16x8 a[4], b[4];
            #pragma unroll
            for (int i = 0; i < 4; ++i) {
                const int r = wr * 64 + i * 16 + mb;
                a[i] = *(const bf16x8*)(rA + r * 128 + ((((kk << 2) + g) ^ (r & 7)) << 4));
            }
            #pragma unroll
            for (int q = 0; q < 4; ++q) {
                const int r = wc * 64 + q * 16 + mb;
                b[q] = *(const bf16x8*)(rB + r * 128 + ((((kk << 2) + g) ^ (r & 7)) << 4));
            }
            #pragma unroll
            for (int i = 0; i < 4; ++i)
                #pragma unroll
                for (int q = 0; q < 4; ++q)
                    acc[i][q] = __builtin_amdgcn_mfma_f32_16x16x32_bf16(a[i], b[q], acc[i][q], 0, 0, 0);
        }
        __syncthreads();
        cur ^= 1;
    }

    #pragma unroll
    for (int i = 0; i < 4; ++i) {
        const int grow = row0 + wr * 64 + i * 16 + ((lane >> 4) << 2);
        #pragma unroll
        for (int q = 0; q < 4; ++q) {
            const int col = col0 + wc * 64 + q * 16 + (lane & 15);
            f32x4 v = acc[i][q];
            const float bv = bias[col];
            ushort4 pk;
            pk.x = f2bf(v[0] + bv); pk.y = f2bf(v[1] + bv);
            pk.z = f2bf(v[2] + bv); pk.w = f2bf(v[3] + bv);
            *(ushort4*)(Ct + ((size_t)((grow >> 11) * 256 + col)) * 2048 + (grow & 2047)) = pk;
        }
    }
}

// ---------------------------------------------------------------------------
// Support GEMM (bf16 A), counted-vmcnt pipeline (unchanged from R10).
// ---------------------------------------------------------------------------
__global__ __launch_bounds__(256) void bgemm_sup_k(
    const u16* __restrict__ A, const u16* __restrict__ Bt,
    const float* __restrict__ bias, u16* __restrict__ Ct)
{
    __shared__ __align__(16) u16 As[2][128][64];
    __shared__ __align__(16) u16 Bs[2][128][64];
    const int K = 256;

    const int tid = threadIdx.x;
    const int wid = tid >> 6, lane = tid & 63;
    const int wr = wid >> 1, wc = wid & 1;
    const int bx = blockIdx.x >> 1, by = blockIdx.x & 1;
    const int row0 = bx * 128, col0 = by * 128;

    const int srow = tid >> 3;
    const int skA = ((tid ^ srow) & 7) << 3;
    const u16* Ag = A + (size_t)(row0 + srow) * K + skA;
    const u16* Bg = Bt + (size_t)(col0 + srow) * K + skA;
    char* ldsA = (char*)&As[0][0][0];
    char* ldsB = (char*)&Bs[0][0][0];
    const int wb = wid << 10;

    f32x4 acc[4][4];
    #pragma unroll
    for (int i = 0; i < 4; ++i)
        #pragma unroll
        for (int q = 0; q < 4; ++q) acc[i][q] = (f32x4){0.f, 0.f, 0.f, 0.f};

    #pragma unroll
    for (int s = 0; s < 4; ++s) {
        async16(Ag + (size_t)(s * 32) * K, ldsA + s * 4096 + wb);
        async16(Bg + (size_t)(s * 32) * K, ldsB + s * 4096 + wb);
    }

    int cur = 0;
    for (int k0 = 0; k0 < K; k0 += 64) {
        if (k0 + 64 < K) {
            char* dA = ldsA + ((cur ^ 1) << 14);
            char* dB = ldsB + ((cur ^ 1) << 14);
            #pragma unroll
            for (int s = 0; s < 4; ++s) {
                async16(Ag + (size_t)(s * 32) * K + k0 + 64, dA + s * 4096 + wb);
                async16(Bg + (size_t)(s * 32) * K + k0 + 64, dB + s * 4096 + wb);
            }
            asm volatile("s_waitcnt vmcnt(8)" ::: "memory");
        } else {
            asm volatile("s_waitcnt vmcnt(0)" ::: "memory");
        }
        __builtin_amdgcn_s_barrier();
        __builtin_amdgcn_sched_barrier(0);
        char* rA = ldsA + (cur << 14);
        char* rB = ldsB + (cur << 14);
        const int mb = lane & 15, g = lane >> 4;
        #pragma unroll
        for (int kk = 0; kk < 2; ++kk) {
            bf16x8 a[4], b[4];
            #pragma unroll
            for (int i = 0; i < 4; ++i) {
                const int r = wr * 64 + i * 16 + mb;
                a[i] = *(const bf16x8*)(rA + r * 128 + ((((kk << 2) + g) ^ (r & 7)) << 4));
            }
            #pragma unroll
            for (int q = 0; q < 4; ++q) {
                const int r = wc * 64 + q * 16 + mb;
                b[q] = *(const bf16x8*)(rB + r * 128 + ((((kk << 2) + g) ^ (r & 7)) << 4));
            }
            #pragma unroll
            for (int i = 0; i < 4; ++i)
                #pragma unroll
                for (int q = 0; q < 4; ++q)
                    acc[i][q] = __builtin_amdgcn_mfma_f32_16x16x32_bf16(a[i], b[q], acc[i][q], 0, 0, 0);
        }
        __builtin_amdgcn_s_barrier();
        cur ^= 1;
    }

    #pragma unroll
    for (int i = 0; i < 4; ++i) {
        const int grow = row0 + wr * 64 + i * 16 + ((lane >> 4) << 2);
        #pragma unroll
        for (int q = 0; q < 4; ++q) {
            const int col = col0 + wc * 64 + q * 16 + (lane & 15);
            f32x4 v = acc[i][q];
            const float bv = bias[col];
            ushort4 pk;
            pk.x = f2bf(v[0] + bv); pk.y = f2bf(v[1] + bv);
            pk.z = f2bf(v[2] + bv); pk.w = f2bf(v[3] + bv);
            *(ushort4*)(Ct + ((size_t)((grow >> 11) * 256 + col)) * 2048 + (grow & 2047)) = pk;
        }
    }
}

// ---------------------------------------------------------------------------
// Adjacency GEMM: counted-vmcnt pipeline + supertile XCD decode (unchanged).
// ---------------------------------------------------------------------------
__global__ __launch_bounds__(256) void bgemm_adj_k(
    const u16* __restrict__ A, const u16* __restrict__ Bt,
    u16* __restrict__ Cx, int K, long long bsB)
{
    __shared__ __align__(16) u16 As[2][128][64];
    __shared__ __align__(16) u16 Bs[2][128][64];

    const int tid = threadIdx.x;
    const int wid = tid >> 6, lane = tid & 63;
    const int wr = wid >> 1, wc = wid & 1;

    const int xcd = blockIdx.x & 7, loc = blockIdx.x >> 3;
    const int s = loc >> 4, w = loc & 15;
    const int sg = xcd * 16 + s;
    const int pzg = sg >> 2, bxg = sg & 3;
    const int bx = bxg * 4 + (w >> 2);
    const int pzidx = pzg * 4 + (w & 3);
    const int by = pzidx >> 6, bz = pzidx & 63;

    const int row0 = bx * 128, col0 = by * 128;
    const u16* Bp = Bt + (long long)bz * bsB;

    const int srow = tid >> 3;
    const int skA = ((tid ^ srow) & 7) << 3;
    const u16* Ag = A + (size_t)(row0 + srow) * K + skA;
    const u16* Bg = Bp + (size_t)(col0 + srow) * K + skA;
    char* ldsA = (char*)&As[0][0][0];
    char* ldsB = (char*)&Bs[0][0][0];
    const int wb = wid << 10;

    f32x4 acc[4][4];
    #pragma unroll
    for (int i = 0; i < 4; ++i)
        #pragma unroll
        for (int q = 0; q < 4; ++q) acc[i][q] = (f32x4){0.f, 0.f, 0.f, 0.f};

    #pragma unroll
    for (int s2 = 0; s2 < 4; ++s2) {
        async16(Ag + (size_t)(s2 * 32) * K, ldsA + s2 * 4096 + wb);
        async16(Bg + (size_t)(s2 * 32) * K, ldsB + s2 * 4096 + wb);
    }

    int cur = 0;
    for (int k0 = 0; k0 < K; k0 += 64) {
        if (k0 + 64 < K) {
            char* dA = ldsA + ((cur ^ 1) << 14);
            char* dB = ldsB + ((cur ^ 1) << 14);
            #pragma unroll
            for (int s2 = 0; s2 < 4; ++s2) {
                async16(Ag + (size_t)(s2 * 32) * K + k0 + 64, dA + s2 * 4096 + wb);
                async16(Bg + (size_t)(s2 * 32) * K + k0 + 64, dB + s2 * 4096 + wb);
            }
            asm volatile("s_waitcnt vmcnt(8)" ::: "memory");
        } else {
            asm volatile("s_waitcnt vmcnt(0)" ::: "memory");
        }
        __builtin_amdgcn_s_barrier();
        __builtin_amdgcn_sched_barrier(0);
        char* rA = ldsA + (cur << 14);
        char* rB = ldsB + (cur << 14);
        const int mb = lane & 15, g = lane >> 4;
        #pragma unroll
        for (int kk = 0; kk < 2; ++kk) {
            bf16x8 a[4], b[4];
            #pragma unroll
            for (int i = 0; i < 4; ++i) {
                const int r = wr * 64 + i * 16 + mb;
                a[i] = *(const bf16x8*)(rA + r * 128 + ((((kk << 2) + g) ^ (r & 7)) << 4));
            }
            #pragma unroll
            for (int q = 0; q < 4; ++q) {
                const int r = wc * 64 + q * 16 + mb;
                b[q] = *(const bf16x8*)(rB + r * 128 + ((((kk << 2) + g) ^ (r & 7)) << 4));
            }
            #pragma unroll
            for (int i = 0; i < 4; ++i)
                #pragma unroll
                for (int q = 0; q < 4; ++q)
                    acc[i][q] = __builtin_amdgcn_mfma_f32_16x16x32_bf16(a[i], b[q], acc[i][q], 0, 0, 0);
        }
        __builtin_amdgcn_s_barrier();
        cur ^= 1;
    }

    #pragma unroll
    for (int i = 0; i < 4; ++i) {
        const int grow = row0 + wr * 64 + i * 16 + ((lane >> 4) << 2);
        #pragma unroll
        for (int q = 0; q < 4; ++q) {
            const int col = col0 + wc * 64 + q * 16 + (lane & 15);
            f32x4 v = acc[i][q];
            #pragma unroll
            for (int r = 0; r < 4; ++r)
                Cx[((size_t)bz * 2048 + grow + r) * 256 + col] = f2bf(fmaxf(v[r], 0.f));
        }
    }
}

// is output position tt overwritten by a later pass?
__device__ __forceinline__ bool keep_out(int p, int tt) {
    if (p == 1) return ((tt & 1) == 0) && (tt % 3 != 2) && ((tt & 3) != 3);
    if (p == 2) return (tt % 3 != 2) && ((tt & 3) != 3);
    if (p == 3) return ((tt & 3) != 3);
    return true;
}

// ---------------------------------------------------------------------------
// LSTM step, A-STATIONARY: block = 128 rows x ALL 1024 gate-cols, 512 thr.
// A panel(s) staged into LDS ONCE ([128][256] x-gather; + [128][256] hprev
// for j>=1), XOR-swizzled (chunk ^ row&7, via per-lane pre-swizzled source).
// Then 8 col-blocks processed with B (weights, L2-hot) loaded DIRECT from
// global into registers -- no barriers in the inner loops, so the compiler
// software-pipelines the b-loads. One __syncthreads per block total.
// Wave layout: 8 waves = 4 row-groups(32) x 2 col-groups(64); per col-block
// each wave computes 32x64 via 2x4 16x16x32 fragments.
// ---------------------------------------------------------------------------
template<int FIRST>
__global__ __launch_bounds__(512) void lstm_astat_k(
    const u16* __restrict__ xsrc, const u16* __restrict__ hprev,
    u16* __restrict__ hnext, float* __restrict__ outF, float* __restrict__ cst,
    const u16* __restrict__ wih, const u16* __restrict__ whh,
    const float* __restrict__ biasp, int nw, int p, int j, int writeH)
{
    __shared__ __align__(16) u16 Als[FIRST ? 1 : 2][128][256];

    const int tid = threadIdx.x;
    const int wid = tid >> 6, lane = tid & 63;
    const int wr = wid >> 1, wc = wid & 1;          // wr 0..3, wc 0..1
    const int row0 = blockIdx.x << 7;
    const unsigned unw = (unsigned)nw;
    const int last = (j == p - 1);

    // ---- stage A panel(s): 8 async16 calls each, LDS linear, source
    // pre-swizzled so LDS[row][c] holds global chunk c ^ (row&7). ----
    {
        char* dst0 = (char*)&Als[0][0][0];
        #pragma unroll
        for (int s = 0; s < 8; ++s) {
            const int rloc = s * 16 + wid * 2 + (lane >> 5);
            const int c = lane & 31;
            const int sc = c ^ (rloc & 7);
            const int n = row0 + rloc;
            const unsigned b = (unsigned)n / unw;
            const int w = n - (int)b * nw;
            const u16* src = xsrc + ((size_t)b * T2 + (size_t)w * p + j) * H2 + sc * 8;
            async16(src, dst0 + s * 8192 + (wid << 10));
        }
        if (!FIRST) {
            char* dst1 = (char*)&Als[FIRST ? 0 : 1][0][0];
            #pragma unroll
            for (int s = 0; s < 8; ++s) {
                const int rloc = s * 16 + wid * 2 + (lane >> 5);
                const int c = lane & 31;
                const int sc = c ^ (rloc & 7);
                const int n = row0 + rloc;
                const u16* src = hprev + (size_t)n * H2 + sc * 8;
                async16(src, dst1 + s * 8192 + (wid << 10));
            }
        }
    }
    __syncthreads();

    const int mb = lane & 15, kq = lane >> 4;       // kq 0..3
    // a-frag LDS base addresses (bytes): row r = wr*32 + i*16 + mb
    int abase[2], axor[2];
    #pragma unroll
    for (int i = 0; i < 2; ++i) {
        const int r = wr * 32 + i * 16 + mb;
        abase[i] = r * 512;
        axor[i] = r & 7;
    }

    const int KS = FIRST ? 8 : 16;                  // K/32 steps

    for (int cb = 0; cb < 8; ++cb) {
        f32x4 acc[2][4];
        #pragma unroll
        for (int i = 0; i < 2; ++i)
            #pragma unroll
            for (int q = 0; q < 4; ++q) acc[i][q] = (f32x4){0.f, 0.f, 0.f, 0.f};

        const int colbase = cb * 128 + wc * 64 + mb;

        #pragma unroll
        for (int ks = 0; ks < 16; ++ks) {
            if (ks >= KS) break;
            const int half = (!FIRST && ks >= 8) ? 1 : 0;
            const int khalf = ks & 7;
            const int g = khalf * 4 + kq;           // global chunk in half
            const char* aL = (const char*)&Als[half][0][0];
            bf16x8 a[2], b[4];
            #pragma unroll
            for (int i = 0; i < 2; ++i)
                a[i] = *(const bf16x8*)(aL + abase[i] + ((g ^ axor[i]) << 4));
            const u16* W = (half == 0) ? wih : whh;
            #pragma unroll
            for (int q = 0; q < 4; ++q)
                b[q] = *(const bf16x8*)(W + (size_t)(colbase + q * 16) * 256
                                          + (khalf << 5) + (kq << 3));
            #pragma unroll
            for (int i = 0; i < 2; ++i)
                #pragma unroll
                for (int q = 0; q < 4; ++q)
                    acc[i][q] = __builtin_amdgcn_mfma_f32_16x16x32_bf16(a[i], b[q], acc[i][q], 0, 0, 0);
        }

        // epilogue for this col-block: frag q = gate q (i,f,g,o)
        const int hu = cb * 32 + wc * 16 + mb;      // hidden unit
        float bq[4];
        #pragma unroll
        for (int q = 0; q < 4; ++q) bq[q] = biasp[cb * 128 + wc * 64 + q * 16 + mb];

        #pragma unroll
        for (int i = 0; i < 2; ++i) {
            const int rbase = row0 + wr * 32 + i * 16 + kq * 4;
            #pragma unroll
            for (int r = 0; r < 4; ++r) {
                const int n = rbase + r;
                const float gi = acc[i][0][r] + bq[0];
                const float gf = acc[i][1][r] + bq[1];
                const float gg = acc[i][2][r] + bq[2];
                const float go = acc[i][3][r] + bq[3];
                const float si = sig_f(gi), sf = sig_f(gf), so = sig_f(go);
                const float tg = tanh_f(gg);
                const float cp = FIRST ? 0.f : cst[(size_t)n * H2 + hu];
                const float cn = sf * cp + si * tg;
                const float hv = so * tanh_f(cn);
                if (writeH) hnext[(size_t)n * H2 + hu] = f2bf(hv);
                if (last) {
                    const unsigned b = (unsigned)n / unw;
                    const int w = n - (int)b * nw;
                    const int tt = w * p + (p - 1);
                    if (keep_out(p, tt))
                        outF[((size_t)b * T2 + tt) * H2 + hu] = hv;
                } else {
                    cst[(size_t)n * H2 + hu] = cn;
                }
            }
        }
    }
}

// update mirror at window-end positions from deferred hnext (bf16 copy)
__global__ __launch_bounds__(256) void scatter_ax_k(
    const u16* __restrict__ hs, u16* __restrict__ mir, int nw, int p, int Nrows)
{
    const int idx = blockIdx.x * 256 + threadIdx.x;
    if (idx >= Nrows * 32) return;
    const int n = idx >> 5, c8 = (idx & 31) << 3;
    const unsigned b = (unsigned)n / (unsigned)nw;
    const int w = n - (int)b * nw;
    *(uint4*)(mir + ((size_t)b * T2 + (size_t)w * p + (p - 1)) * H2 + c8) =
        *(const uint4*)(hs + (size_t)n * H2 + c8);
}

// Wg transpose+cast: out[n][k] = bf16(in[k][n]), 256x256
__global__ __launch_bounds__(256) void convT_k(const float* __restrict__ in, u16* __restrict__ out)
{
    const int idx = blockIdx.x * 256 + threadIdx.x;
    const int r = idx >> 8, c = idx & 255;
    out[(size_t)c * 256 + r] = f2bf(in[idx]);
}

// LSTM weight gate-major permute: wP[pass][n'][k], n' = (h>>4)*64+g*16+(h&15)
__global__ __launch_bounds__(256) void convW_k(
    const float* __restrict__ Wih, const float* __restrict__ Whh,
    u16* __restrict__ wih_p, u16* __restrict__ whh_p)
{
    const int idx = blockIdx.x * 256 + threadIdx.x;
    const int pp = idx >> 18;
    const int np = (idx >> 8) & 1023;
    const int k = idx & 255;
    const int group = np >> 6, g = (np >> 4) & 3, uu = np & 15;
    const int hh = group * 16 + uu;
    const size_t src = (size_t)pp * 262144 + (size_t)(g * 256 + hh) * 256 + k;
    wih_p[idx] = f2bf(Wih[src]);
    whh_p[idx] = f2bf(Whh[src]);
}

__global__ __launch_bounds__(256) void convB_k(
    const float* __restrict__ bih, const float* __restrict__ bhh, float* __restrict__ bp)
{
    const int idx = blockIdx.x * 256 + threadIdx.x;
    const int pp = idx >> 10, np = idx & 1023;
    const int group = np >> 6, g = (np >> 4) & 3, uu = np & 15;
    const int hh = group * 16 + uu;
    bp[idx] = bih[pp * 1024 + g * 256 + hh] + bhh[pp * 1024 + g * 256 + hh];
}

// ---------------------------------------------------------------------------
extern "C" void kernel_launch(void* const* d_in, const int* in_sizes, int n_in,
                              void* d_out, int out_size, void* d_ws, size_t ws_size,
                              hipStream_t stream)
{
    const float* x   = (const float*)d_in[0];
    const float* adj = (const float*)d_in[1];
    const float* Wg0 = (const float*)d_in[2];
    const float* bg0 = (const float*)d_in[3];
    const float* Wg1 = (const float*)d_in[4];
    const float* bg1 = (const float*)d_in[5];
    const float* Wih = (const float*)d_in[6];
    const float* Whh = (const float*)d_in[7];
    const float* bih = (const float*)d_in[8];
    const float* bhh = (const float*)d_in[9];
    float* out = (float*)d_out;

    char* ws = (char*)d_ws;
    u16*   Ax   = (u16*)ws;                         // 67MB: GCN h mirror; p>=2 ping-pong
    u16*   hs0  = Ax;
    u16*   hs1  = (u16*)(ws + 33554432);
    u16*   hsB  = (u16*)(ws + 67108864);            // 67MB: St (GCN) / t-indexed mirror (LSTM)
    float* cst  = (float*)(ws + 134217728);         // 67MB: f32 cell state
    char*  wreg = ws + 201326592;                   // 8MB region
    u16*   adjbf = (u16*)wreg;                      //   GCN phase
    u16*   wihP  = (u16*)wreg;                      //   LSTM phase (adjbf dead)
    u16*   whhP  = (u16*)(wreg + 2097152);
    float* bp    = (float*)(wreg + 4194304);
    u16*   wg0t  = (u16*)(ws + 209715200);
    u16*   wg1t  = (u16*)(ws + 209846272);
    u16*   St    = hsB;

    // ---- casts / weight prep ----
    cast_bf16_k<<<4096, 256, 0, stream>>>(adj, adjbf, 1048576);
    convT_k<<<256, 256, 0, stream>>>(Wg0, wg0t);
    convT_k<<<256, 256, 0, stream>>>(Wg1, wg1t);

    // ---- GCN ----
    bgemm_sup_f32a_k<<<2048, 256, 0, stream>>>(x, wg0t, bg0, St);
    bgemm_adj_k<<<2048, 256, 0, stream>>>(adjbf, St, Ax, 2048, (long long)256 * 2048);
    bgemm_sup_k<<<2048, 256, 0, stream>>>(Ax, wg1t, bg1, St);
    bgemm_adj_k<<<2048, 256, 0, stream>>>(adjbf, St, Ax, 2048, (long long)256 * 2048);

    // ---- LSTM weights (adjbf dead) ----
    convW_k<<<4096, 256, 0, stream>>>(Wih, Whh, wihP, whhP);
    convB_k<<<16, 256, 0, stream>>>(bih, bhh, bp);

    // ---- skip-LSTM passes ----
    for (int p = 1; p <= MAXP; ++p) {
        const int nw = T2 / p;
        const int Nrows = 64 * nw;                  // 131072 / 65536 / 43648 / 32768
        const int nblk = Nrows / 128;               // 1024 / 512 / 341 / 256
        const u16* wihp = wihP + (size_t)(p - 1) * 262144;
        const u16* whhp = whhP + (size_t)(p - 1) * 262144;
        const float* bpp = bp + (size_t)(p - 1) * 1024;
        const u16* xs = (p == 1) ? Ax : hsB;
        for (int j = 0; j < p; ++j) {
            u16* hn = (p == 1) ? hsB : ((j & 1) ? hs1 : hs0);
            const u16* hpv = (j == 0) ? nullptr : ((j & 1) ? hs0 : hs1);
            const int writeH = !(p == MAXP && j == p - 1);
            if (j == 0)
                lstm_astat_k<1><<<nblk, 512, 0, stream>>>(
                    xs, hpv, hn, out, cst, wihp, whhp, bpp, nw, p, j, writeH);
            else
                lstm_astat_k<0><<<nblk, 512, 0, stream>>>(
                    xs, hpv, hn, out, cst, wihp, whhp, bpp, nw, p, j, writeH);
        }
        if (p >= 2 && p != MAXP) {
            const u16* hlast = ((p - 1) & 1) ? hs1 : hs0;
            scatter_ax_k<<<(Nrows * 32 + 255) / 256, 256, 0, stream>>>(hlast, hsB, nw, p, Nrows);
        }
    }
}

// Round 13
// 1248.967 us; speedup vs baseline: 1.9700x; 1.9700x over previous
//
#include <hip/hip_runtime.h>
#include <hip/hip_bf16.h>

#define T2 2048
#define H2 256
#define BT2 131072          // B*T = 64*2048
#define MAXP 4

typedef __attribute__((ext_vector_type(8))) short bf16x8;
typedef __attribute__((ext_vector_type(4))) float f32x4;
typedef unsigned short u16;

__device__ __forceinline__ u16 f2bf(float f) {
    union { float f; unsigned u; } v; v.f = f;
    unsigned r = (v.u + 0x7FFFu + ((v.u >> 16) & 1u)) >> 16;
    return (u16)r;
}
__device__ __forceinline__ void async16(const void* g, void* l) {
    __builtin_amdgcn_global_load_lds((const __attribute__((address_space(1))) void*)g,
                                     (__attribute__((address_space(3))) void*)l, 16, 0, 0);
}
__device__ __forceinline__ float frcp(float x) { return __builtin_amdgcn_rcpf(x); }
__device__ __forceinline__ float sig_f(float x) { return frcp(1.f + __expf(-x)); }
__device__ __forceinline__ float tanh_f(float x) {
    return 1.f - 2.f * frcp(__expf(2.f * x) + 1.f);
}

// f32 -> bf16 cast, 4 elems/thread (adjacency only)
__global__ __launch_bounds__(256) void cast_bf16_k(
    const float* __restrict__ in, u16* __restrict__ out, int n4)
{
    const int i = blockIdx.x * 256 + threadIdx.x;
    if (i >= n4) return;
    const float4 v = ((const float4*)in)[i];
    ushort4 h;
    h.x = f2bf(v.x); h.y = f2bf(v.y); h.z = f2bf(v.z); h.w = f2bf(v.w);
    ((ushort4*)out)[i] = h;
}

// ---------------------------------------------------------------------------
// Support GEMM 1, fused f32-A (__syncthreads kept: ds_write staging needs
// the lgkm drain): C^T = (x_f32 @ Bt^T + bias) -> bf16 St.
// ---------------------------------------------------------------------------
__global__ __launch_bounds__(256) void bgemm_sup_f32a_k(
    const float* __restrict__ A, const u16* __restrict__ Bt,
    const float* __restrict__ bias, u16* __restrict__ Ct)
{
    __shared__ __align__(16) u16 As[2][128][64];
    __shared__ __align__(16) u16 Bs[2][128][64];
    const int K = 256;

    const int tid = threadIdx.x;
    const int wid = tid >> 6, lane = tid & 63;
    const int wr = wid >> 1, wc = wid & 1;
    const int bx = blockIdx.x >> 1, by = blockIdx.x & 1;
    const int row0 = bx * 128, col0 = by * 128;

    const int srow = tid >> 3;
    const int skA = ((tid ^ srow) & 7) << 3;
    const float* Agf = A + (size_t)(row0 + srow) * K + skA;
    const u16* Bg = Bt + (size_t)(col0 + srow) * K + skA;
    char* ldsA = (char*)&As[0][0][0];
    char* ldsB = (char*)&Bs[0][0][0];
    const int wb = wid << 10;
    const int awr = srow * 128 + (tid & 7) * 16;

    f32x4 acc[4][4];
    #pragma unroll
    for (int i = 0; i < 4; ++i)
        #pragma unroll
        for (int q = 0; q < 4; ++q) acc[i][q] = (f32x4){0.f, 0.f, 0.f, 0.f};

    #pragma unroll
    for (int s = 0; s < 4; ++s) {
        const float4 u0 = *(const float4*)(Agf + (size_t)(s * 32) * K);
        const float4 u1 = *(const float4*)(Agf + (size_t)(s * 32) * K + 4);
        ushort4 h0, h1;
        h0.x = f2bf(u0.x); h0.y = f2bf(u0.y); h0.z = f2bf(u0.z); h0.w = f2bf(u0.w);
        h1.x = f2bf(u1.x); h1.y = f2bf(u1.y); h1.z = f2bf(u1.z); h1.w = f2bf(u1.w);
        *(ushort4*)(ldsA + s * 4096 + awr) = h0;
        *(ushort4*)(ldsA + s * 4096 + awr + 8) = h1;
        async16(Bg + (size_t)(s * 32) * K, ldsB + s * 4096 + wb);
    }
    __syncthreads();

    int cur = 0;
    for (int k0 = 0; k0 < K; k0 += 64) {
        if (k0 + 64 < K) {
            char* dA = ldsA + ((cur ^ 1) << 14);
            char* dB = ldsB + ((cur ^ 1) << 14);
            #pragma unroll
            for (int s = 0; s < 4; ++s) {
                const float4 u0 = *(const float4*)(Agf + (size_t)(s * 32) * K + k0 + 64);
                const float4 u1 = *(const float4*)(Agf + (size_t)(s * 32) * K + k0 + 68);
                ushort4 h0, h1;
                h0.x = f2bf(u0.x); h0.y = f2bf(u0.y); h0.z = f2bf(u0.z); h0.w = f2bf(u0.w);
                h1.x = f2bf(u1.x); h1.y = f2bf(u1.y); h1.z = f2bf(u1.z); h1.w = f2bf(u1.w);
                *(ushort4*)(dA + s * 4096 + awr) = h0;
                *(ushort4*)(dA + s * 4096 + awr + 8) = h1;
                async16(Bg + (size_t)(s * 32) * K + k0 + 64, dB + s * 4096 + wb);
            }
        }
        char* rA = ldsA + (cur << 14);
        char* rB = ldsB + (cur << 14);
        const int mb = lane & 15, g = lane >> 4;
        #pragma unroll
        for (int kk = 0; kk < 2; ++kk) {
            bf16x8 a[4], b[4];
            #pragma unroll
            for (int i = 0; i < 4; ++i) {
                const int r = wr * 64 + i * 16 + mb;
                a[i] = *(const bf16x8*)(rA + r * 128 + ((((kk << 2) + g) ^ (r & 7)) << 4));
            }
            #pragma unroll
            for (int q = 0; q < 4; ++q) {
                const int r = wc * 64 + q * 16 + mb;
                b[q] = *(const bf16x8*)(rB + r * 128 + ((((kk << 2) + g) ^ (r & 7)) << 4));
            }
            #pragma unroll
            for (int i = 0; i < 4; ++i)
                #pragma unroll
                for (int q = 0; q < 4; ++q)
                    acc[i][q] = __builtin_amdgcn_mfma_f32_16x16x32_bf16(a[i], b[q], acc[i][q], 0, 0, 0);
        }
        __syncthreads();
        cur ^= 1;
    }

    #pragma unroll
    for (int i = 0; i < 4; ++i) {
        const int grow = row0 + wr * 64 + i * 16 + ((lane >> 4) << 2);
        #pragma unroll
        for (int q = 0; q < 4; ++q) {
            const int col = col0 + wc * 64 + q * 16 + (lane & 15);
            f32x4 v = acc[i][q];
            const float bv = bias[col];
            ushort4 pk;
            pk.x = f2bf(v[0] + bv); pk.y = f2bf(v[1] + bv);
            pk.z = f2bf(v[2] + bv); pk.w = f2bf(v[3] + bv);
            *(ushort4*)(Ct + ((size_t)((grow >> 11) * 256 + col)) * 2048 + (grow & 2047)) = pk;
        }
    }
}

// ---------------------------------------------------------------------------
// Support GEMM (bf16 A), counted-vmcnt pipeline: C^T = (A @ Bt^T + bias) -> St.
// ---------------------------------------------------------------------------
__global__ __launch_bounds__(256) void bgemm_sup_k(
    const u16* __restrict__ A, const u16* __restrict__ Bt,
    const float* __restrict__ bias, u16* __restrict__ Ct)
{
    __shared__ __align__(16) u16 As[2][128][64];
    __shared__ __align__(16) u16 Bs[2][128][64];
    const int K = 256;

    const int tid = threadIdx.x;
    const int wid = tid >> 6, lane = tid & 63;
    const int wr = wid >> 1, wc = wid & 1;
    const int bx = blockIdx.x >> 1, by = blockIdx.x & 1;
    const int row0 = bx * 128, col0 = by * 128;

    const int srow = tid >> 3;
    const int skA = ((tid ^ srow) & 7) << 3;
    const u16* Ag = A + (size_t)(row0 + srow) * K + skA;
    const u16* Bg = Bt + (size_t)(col0 + srow) * K + skA;
    char* ldsA = (char*)&As[0][0][0];
    char* ldsB = (char*)&Bs[0][0][0];
    const int wb = wid << 10;

    f32x4 acc[4][4];
    #pragma unroll
    for (int i = 0; i < 4; ++i)
        #pragma unroll
        for (int q = 0; q < 4; ++q) acc[i][q] = (f32x4){0.f, 0.f, 0.f, 0.f};

    #pragma unroll
    for (int s = 0; s < 4; ++s) {
        async16(Ag + (size_t)(s * 32) * K, ldsA + s * 4096 + wb);
        async16(Bg + (size_t)(s * 32) * K, ldsB + s * 4096 + wb);
    }

    int cur = 0;
    for (int k0 = 0; k0 < K; k0 += 64) {
        if (k0 + 64 < K) {
            char* dA = ldsA + ((cur ^ 1) << 14);
            char* dB = ldsB + ((cur ^ 1) << 14);
            #pragma unroll
            for (int s = 0; s < 4; ++s) {
                async16(Ag + (size_t)(s * 32) * K + k0 + 64, dA + s * 4096 + wb);
                async16(Bg + (size_t)(s * 32) * K + k0 + 64, dB + s * 4096 + wb);
            }
            asm volatile("s_waitcnt vmcnt(8)" ::: "memory");
        } else {
            asm volatile("s_waitcnt vmcnt(0)" ::: "memory");
        }
        __builtin_amdgcn_s_barrier();
        __builtin_amdgcn_sched_barrier(0);
        char* rA = ldsA + (cur << 14);
        char* rB = ldsB + (cur << 14);
        const int mb = lane & 15, g = lane >> 4;
        #pragma unroll
        for (int kk = 0; kk < 2; ++kk) {
            bf16x8 a[4], b[4];
            #pragma unroll
            for (int i = 0; i < 4; ++i) {
                const int r = wr * 64 + i * 16 + mb;
                a[i] = *(const bf16x8*)(rA + r * 128 + ((((kk << 2) + g) ^ (r & 7)) << 4));
            }
            #pragma unroll
            for (int q = 0; q < 4; ++q) {
                const int r = wc * 64 + q * 16 + mb;
                b[q] = *(const bf16x8*)(rB + r * 128 + ((((kk << 2) + g) ^ (r & 7)) << 4));
            }
            #pragma unroll
            for (int i = 0; i < 4; ++i)
                #pragma unroll
                for (int q = 0; q < 4; ++q)
                    acc[i][q] = __builtin_amdgcn_mfma_f32_16x16x32_bf16(a[i], b[q], acc[i][q], 0, 0, 0);
        }
        __builtin_amdgcn_s_barrier();
        cur ^= 1;
    }

    #pragma unroll
    for (int i = 0; i < 4; ++i) {
        const int grow = row0 + wr * 64 + i * 16 + ((lane >> 4) << 2);
        #pragma unroll
        for (int q = 0; q < 4; ++q) {
            const int col = col0 + wc * 64 + q * 16 + (lane & 15);
            f32x4 v = acc[i][q];
            const float bv = bias[col];
            ushort4 pk;
            pk.x = f2bf(v[0] + bv); pk.y = f2bf(v[1] + bv);
            pk.z = f2bf(v[2] + bv); pk.w = f2bf(v[3] + bv);
            *(ushort4*)(Ct + ((size_t)((grow >> 11) * 256 + col)) * 2048 + (grow & 2047)) = pk;
        }
    }
}

// ---------------------------------------------------------------------------
// Adjacency GEMM: counted-vmcnt pipeline + supertile XCD decode.
// ---------------------------------------------------------------------------
__global__ __launch_bounds__(256) void bgemm_adj_k(
    const u16* __restrict__ A, const u16* __restrict__ Bt,
    u16* __restrict__ Cx, int K, long long bsB)
{
    __shared__ __align__(16) u16 As[2][128][64];
    __shared__ __align__(16) u16 Bs[2][128][64];

    const int tid = threadIdx.x;
    const int wid = tid >> 6, lane = tid & 63;
    const int wr = wid >> 1, wc = wid & 1;

    const int xcd = blockIdx.x & 7, loc = blockIdx.x >> 3;
    const int s = loc >> 4, w = loc & 15;
    const int sg = xcd * 16 + s;
    const int pzg = sg >> 2, bxg = sg & 3;
    const int bx = bxg * 4 + (w >> 2);
    const int pzidx = pzg * 4 + (w & 3);
    const int by = pzidx >> 6, bz = pzidx & 63;

    const int row0 = bx * 128, col0 = by * 128;
    const u16* Bp = Bt + (long long)bz * bsB;

    const int srow = tid >> 3;
    const int skA = ((tid ^ srow) & 7) << 3;
    const u16* Ag = A + (size_t)(row0 + srow) * K + skA;
    const u16* Bg = Bp + (size_t)(col0 + srow) * K + skA;
    char* ldsA = (char*)&As[0][0][0];
    char* ldsB = (char*)&Bs[0][0][0];
    const int wb = wid << 10;

    f32x4 acc[4][4];
    #pragma unroll
    for (int i = 0; i < 4; ++i)
        #pragma unroll
        for (int q = 0; q < 4; ++q) acc[i][q] = (f32x4){0.f, 0.f, 0.f, 0.f};

    #pragma unroll
    for (int s2 = 0; s2 < 4; ++s2) {
        async16(Ag + (size_t)(s2 * 32) * K, ldsA + s2 * 4096 + wb);
        async16(Bg + (size_t)(s2 * 32) * K, ldsB + s2 * 4096 + wb);
    }

    int cur = 0;
    for (int k0 = 0; k0 < K; k0 += 64) {
        if (k0 + 64 < K) {
            char* dA = ldsA + ((cur ^ 1) << 14);
            char* dB = ldsB + ((cur ^ 1) << 14);
            #pragma unroll
            for (int s2 = 0; s2 < 4; ++s2) {
                async16(Ag + (size_t)(s2 * 32) * K + k0 + 64, dA + s2 * 4096 + wb);
                async16(Bg + (size_t)(s2 * 32) * K + k0 + 64, dB + s2 * 4096 + wb);
            }
            asm volatile("s_waitcnt vmcnt(8)" ::: "memory");
        } else {
            asm volatile("s_waitcnt vmcnt(0)" ::: "memory");
        }
        __builtin_amdgcn_s_barrier();
        __builtin_amdgcn_sched_barrier(0);
        char* rA = ldsA + (cur << 14);
        char* rB = ldsB + (cur << 14);
        const int mb = lane & 15, g = lane >> 4;
        #pragma unroll
        for (int kk = 0; kk < 2; ++kk) {
            bf16x8 a[4], b[4];
            #pragma unroll
            for (int i = 0; i < 4; ++i) {
                const int r = wr * 64 + i * 16 + mb;
                a[i] = *(const bf16x8*)(rA + r * 128 + ((((kk << 2) + g) ^ (r & 7)) << 4));
            }
            #pragma unroll
            for (int q = 0; q < 4; ++q) {
                const int r = wc * 64 + q * 16 + mb;
                b[q] = *(const bf16x8*)(rB + r * 128 + ((((kk << 2) + g) ^ (r & 7)) << 4));
            }
            #pragma unroll
            for (int i = 0; i < 4; ++i)
                #pragma unroll
                for (int q = 0; q < 4; ++q)
                    acc[i][q] = __builtin_amdgcn_mfma_f32_16x16x32_bf16(a[i], b[q], acc[i][q], 0, 0, 0);
        }
        __builtin_amdgcn_s_barrier();
        cur ^= 1;
    }

    #pragma unroll
    for (int i = 0; i < 4; ++i) {
        const int grow = row0 + wr * 64 + i * 16 + ((lane >> 4) << 2);
        #pragma unroll
        for (int q = 0; q < 4; ++q) {
            const int col = col0 + wc * 64 + q * 16 + (lane & 15);
            f32x4 v = acc[i][q];
            #pragma unroll
            for (int r = 0; r < 4; ++r)
                Cx[((size_t)bz * 2048 + grow + r) * 256 + col] = f2bf(fmaxf(v[r], 0.f));
        }
    }
}

// is output position tt overwritten by a later pass?
__device__ __forceinline__ bool keep_out(int p, int tt) {
    if (p == 1) return ((tt & 1) == 0) && (tt % 3 != 2) && ((tt & 3) != 3);
    if (p == 2) return (tt % 3 != 2) && ((tt & 3) != 3);
    if (p == 3) return ((tt & 3) != 3);
    return true;
}

// ---------------------------------------------------------------------------
// LSTM step, M=128 tile, counted-vmcnt pipeline (8 loads/step), 64KB LDS ->
// 2 blocks/CU (verified correct at p=3 in R10; now used for ALL passes —
// the 2nd resident block's MFMA covers stage latency + epilogue).
// ---------------------------------------------------------------------------
__global__ __launch_bounds__(256) void lstm_step_k(
    const u16* __restrict__ xsrc, const u16* __restrict__ hprev,
    u16* __restrict__ hnext, float* __restrict__ outF, float* __restrict__ cst,
    const u16* __restrict__ wih, const u16* __restrict__ whh,
    const float* __restrict__ biasp, int nw, int p, int j, int cpx, int writeH)
{
    __shared__ __align__(16) u16 As[2][128][64];
    __shared__ __align__(16) u16 Bs[2][128][64];

    const int tid = threadIdx.x;
    const int wid = tid >> 6, lane = tid & 63;
    const int wr = wid >> 1, wc = wid & 1;

    const int l = (blockIdx.x & 7) * cpx + (blockIdx.x >> 3);
    const int col0 = (l & 7) << 7;
    const int row0 = (l >> 3) << 7;
    const int first = (j == 0), last = (j == p - 1);

    const int srow = tid >> 3;
    const int skA = ((tid ^ srow) & 7) << 3;
    const unsigned unw = (unsigned)nw;

    const u16* axp[4];
    const u16* hpp[4];
    size_t wrow[4];
    #pragma unroll
    for (int s = 0; s < 4; ++s) {
        const int r = srow + 32 * s;
        const int n = row0 + r;
        const unsigned b = (unsigned)n / unw;
        const int w = n - (int)b * nw;
        axp[s] = xsrc + ((size_t)b * T2 + (size_t)w * p + j) * H2 + skA;
        hpp[s] = hprev ? hprev + (size_t)n * H2 + skA : nullptr;
        wrow[s] = (size_t)(col0 + r) * H2 + skA;
    }
    char* ldsA = (char*)&As[0][0][0];
    char* ldsB = (char*)&Bs[0][0][0];
    const int wb = wid << 10;

    f32x4 acc[4][4];
    #pragma unroll
    for (int i = 0; i < 4; ++i)
        #pragma unroll
        for (int q = 0; q < 4; ++q) acc[i][q] = (f32x4){0.f, 0.f, 0.f, 0.f};

    const int KT = first ? 256 : 512;

    // prologue: stage tile 0 (x-part) into buf 0 -- 8 loads/wave
    #pragma unroll
    for (int s = 0; s < 4; ++s) {
        async16(axp[s], ldsA + s * 4096 + wb);
        async16(wih + wrow[s], ldsB + s * 4096 + wb);
    }

    int cur = 0;
    for (int k0 = 0; k0 < KT; k0 += 64) {
        const int kn = k0 + 64;
        if (kn < KT) {
            char* dA = ldsA + ((cur ^ 1) << 14);
            char* dB = ldsB + ((cur ^ 1) << 14);
            if (kn < 256) {
                #pragma unroll
                for (int s = 0; s < 4; ++s) {
                    async16(axp[s] + kn, dA + s * 4096 + wb);
                    async16(wih + wrow[s] + kn, dB + s * 4096 + wb);
                }
            } else {
                const int kk2 = kn - 256;
                #pragma unroll
                for (int s = 0; s < 4; ++s) {
                    async16(hpp[s] + kk2, dA + s * 4096 + wb);
                    async16(whh + wrow[s] + kk2, dB + s * 4096 + wb);
                }
            }
            asm volatile("s_waitcnt vmcnt(8)" ::: "memory");
        } else {
            asm volatile("s_waitcnt vmcnt(0)" ::: "memory");
        }
        __builtin_amdgcn_s_barrier();
        __builtin_amdgcn_sched_barrier(0);
        char* rA = ldsA + (cur << 14);
        char* rB = ldsB + (cur << 14);
        const int mb = lane & 15, g = lane >> 4;
        #pragma unroll
        for (int kk = 0; kk < 2; ++kk) {
            bf16x8 a[4], b[4];
            #pragma unroll
            for (int i = 0; i < 4; ++i) {
                const int r = wr * 64 + i * 16 + mb;
                a[i] = *(const bf16x8*)(rA + r * 128 + ((((kk << 2) + g) ^ (r & 7)) << 4));
            }
            #pragma unroll
            for (int q = 0; q < 4; ++q) {
                const int r = wc * 64 + q * 16 + mb;
                b[q] = *(const bf16x8*)(rB + r * 128 + ((((kk << 2) + g) ^ (r & 7)) << 4));
            }
            #pragma unroll
            for (int i = 0; i < 4; ++i)
                #pragma unroll
                for (int q = 0; q < 4; ++q)
                    acc[i][q] = __builtin_amdgcn_mfma_f32_16x16x32_bf16(a[i], b[q], acc[i][q], 0, 0, 0);
        }
        __builtin_amdgcn_s_barrier();
        cur ^= 1;
    }

    const int u = lane & 15;
    const int colb = col0 + wc * 64;
    const int hu = (colb >> 2) + u;
    float bq[4];
    #pragma unroll
    for (int q = 0; q < 4; ++q) bq[q] = biasp[colb + q * 16 + u];

    #pragma unroll
    for (int i = 0; i < 4; ++i) {
        const int rbase = row0 + wr * 64 + i * 16 + ((lane >> 4) << 2);
        #pragma unroll
        for (int r = 0; r < 4; ++r) {
            const int n = rbase + r;
            const float gi = acc[i][0][r] + bq[0];
            const float gf = acc[i][1][r] + bq[1];
            const float gg = acc[i][2][r] + bq[2];
            const float go = acc[i][3][r] + bq[3];
            const float si = sig_f(gi), sf = sig_f(gf), so = sig_f(go);
            const float tg = tanh_f(gg);
            const float cp = first ? 0.f : cst[(size_t)n * H2 + hu];
            const float cn = sf * cp + si * tg;
            const float hv = so * tanh_f(cn);
            if (writeH) hnext[(size_t)n * H2 + hu] = f2bf(hv);
            if (last) {
                const unsigned b = (unsigned)n / unw;
                const int w = n - (int)b * nw;
                const int tt = w * p + (p - 1);
                if (keep_out(p, tt))
                    outF[((size_t)b * T2 + tt) * H2 + hu] = hv;
            } else {
                cst[(size_t)n * H2 + hu] = cn;
            }
        }
    }
}

// update mirror at window-end positions from deferred hnext (bf16 copy)
__global__ __launch_bounds__(256) void scatter_ax_k(
    const u16* __restrict__ hs, u16* __restrict__ mir, int nw, int p, int Nrows)
{
    const int idx = blockIdx.x * 256 + threadIdx.x;
    if (idx >= Nrows * 32) return;
    const int n = idx >> 5, c8 = (idx & 31) << 3;
    const unsigned b = (unsigned)n / (unsigned)nw;
    const int w = n - (int)b * nw;
    *(uint4*)(mir + ((size_t)b * T2 + (size_t)w * p + (p - 1)) * H2 + c8) =
        *(const uint4*)(hs + (size_t)n * H2 + c8);
}

// Wg transpose+cast: out[n][k] = bf16(in[k][n]), 256x256
__global__ __launch_bounds__(256) void convT_k(const float* __restrict__ in, u16* __restrict__ out)
{
    const int idx = blockIdx.x * 256 + threadIdx.x;
    const int r = idx >> 8, c = idx & 255;
    out[(size_t)c * 256 + r] = f2bf(in[idx]);
}

// LSTM weight gate-major permute: wP[pass][n'][k], n' = (h>>4)*64+g*16+(h&15)
__global__ __launch_bounds__(256) void convW_k(
    const float* __restrict__ Wih, const float* __restrict__ Whh,
    u16* __restrict__ wih_p, u16* __restrict__ whh_p)
{
    const int idx = blockIdx.x * 256 + threadIdx.x;
    const int pp = idx >> 18;
    const int np = (idx >> 8) & 1023;
    const int k = idx & 255;
    const int group = np >> 6, g = (np >> 4) & 3, uu = np & 15;
    const int hh = group * 16 + uu;
    const size_t src = (size_t)pp * 262144 + (size_t)(g * 256 + hh) * 256 + k;
    wih_p[idx] = f2bf(Wih[src]);
    whh_p[idx] = f2bf(Whh[src]);
}

__global__ __launch_bounds__(256) void convB_k(
    const float* __restrict__ bih, const float* __restrict__ bhh, float* __restrict__ bp)
{
    const int idx = blockIdx.x * 256 + threadIdx.x;
    const int pp = idx >> 10, np = idx & 1023;
    const int group = np >> 6, g = (np >> 4) & 3, uu = np & 15;
    const int hh = group * 16 + uu;
    bp[idx] = bih[pp * 1024 + g * 256 + hh] + bhh[pp * 1024 + g * 256 + hh];
}

// ---------------------------------------------------------------------------
extern "C" void kernel_launch(void* const* d_in, const int* in_sizes, int n_in,
                              void* d_out, int out_size, void* d_ws, size_t ws_size,
                              hipStream_t stream)
{
    const float* x   = (const float*)d_in[0];
    const float* adj = (const float*)d_in[1];
    const float* Wg0 = (const float*)d_in[2];
    const float* bg0 = (const float*)d_in[3];
    const float* Wg1 = (const float*)d_in[4];
    const float* bg1 = (const float*)d_in[5];
    const float* Wih = (const float*)d_in[6];
    const float* Whh = (const float*)d_in[7];
    const float* bih = (const float*)d_in[8];
    const float* bhh = (const float*)d_in[9];
    float* out = (float*)d_out;

    char* ws = (char*)d_ws;
    u16*   Ax   = (u16*)ws;                         // 67MB: GCN h mirror; p>=2 ping-pong
    u16*   hs0  = Ax;
    u16*   hs1  = (u16*)(ws + 33554432);
    u16*   hsB  = (u16*)(ws + 67108864);            // 67MB: St (GCN) / t-indexed mirror (LSTM)
    float* cst  = (float*)(ws + 134217728);         // 67MB: f32 cell state
    char*  wreg = ws + 201326592;                   // 8MB region
    u16*   adjbf = (u16*)wreg;                      //   GCN phase
    u16*   wihP  = (u16*)wreg;                      //   LSTM phase (adjbf dead)
    u16*   whhP  = (u16*)(wreg + 2097152);
    float* bp    = (float*)(wreg + 4194304);
    u16*   wg0t  = (u16*)(ws + 209715200);
    u16*   wg1t  = (u16*)(ws + 209846272);
    u16*   St    = hsB;

    // ---- casts / weight prep ----
    cast_bf16_k<<<4096, 256, 0, stream>>>(adj, adjbf, 1048576);
    convT_k<<<256, 256, 0, stream>>>(Wg0, wg0t);
    convT_k<<<256, 256, 0, stream>>>(Wg1, wg1t);

    // ---- GCN ----
    bgemm_sup_f32a_k<<<2048, 256, 0, stream>>>(x, wg0t, bg0, St);
    bgemm_adj_k<<<2048, 256, 0, stream>>>(adjbf, St, Ax, 2048, (long long)256 * 2048);
    bgemm_sup_k<<<2048, 256, 0, stream>>>(Ax, wg1t, bg1, St);
    bgemm_adj_k<<<2048, 256, 0, stream>>>(adjbf, St, Ax, 2048, (long long)256 * 2048);

    // ---- LSTM weights (adjbf dead) ----
    convW_k<<<4096, 256, 0, stream>>>(Wih, Whh, wihP, whhP);
    convB_k<<<16, 256, 0, stream>>>(bih, bhh, bp);

    // ---- skip-LSTM passes ----
    for (int p = 1; p <= MAXP; ++p) {
        const int nw = T2 / p;
        const int Nrows = 64 * nw;                  // 131072 / 65536 / 43648 / 32768
        const int cpx = Nrows / 128;                // 1024 / 512 / 341 / 256
        const u16* wihp = wihP + (size_t)(p - 1) * 262144;
        const u16* whhp = whhP + (size_t)(p - 1) * 262144;
        const float* bpp = bp + (size_t)(p - 1) * 1024;
        const u16* xs = (p == 1) ? Ax : hsB;
        for (int j = 0; j < p; ++j) {
            u16* hn = (p == 1) ? hsB : ((j & 1) ? hs1 : hs0);
            const u16* hpv = (j == 0) ? nullptr : ((j & 1) ? hs0 : hs1);
            const int writeH = !(p == MAXP && j == p - 1);
            lstm_step_k<<<cpx * 8, 256, 0, stream>>>(
                xs, hpv, hn, out, cst, wihp, whhp, bpp, nw, p, j, cpx, writeH);
        }
        if (p >= 2 && p != MAXP) {
            const u16* hlast = ((p - 1) & 1) ? hs1 : hs0;
            scatter_ax_k<<<(Nrows * 32 + 255) / 256, 256, 0, stream>>>(hlast, hsB, nw, p, Nrows);
        }
    }
}